// Round 1
// baseline (352.605 us; speedup 1.0000x reference)
//
#include <hip/hip_runtime.h>
#include <stdint.h>

// Problem constants
constexpr int C_IN  = 512;
constexpr int HW    = 784;            // 28*28 (1x1 conv, VALID -> same spatial)
constexpr int NB    = 32;             // batch
constexpr int M_TOT = NB * HW;        // 25088
constexpr int N_TOT = 2000;           // out channels
constexpr int IMG_STRIDE = C_IN * HW; // floats per input image
constexpr int OUT_BATCH  = N_TOT * HW;

// GEMM tiling
#define BM 128
#define BN 128
#define BK 64

typedef __attribute__((ext_vector_type(8))) short bf16x8;
typedef __attribute__((ext_vector_type(4))) float f32x4;

__device__ __forceinline__ uint16_t f2bf(float f) {
    union { float f; uint32_t u; } x; x.f = f;
    return (uint16_t)((x.u + 0x8000u) >> 16);   // round-half-up to bf16 (no NaN in data)
}

// ---------------------------------------------------------------------------
// s2[m] = sum_c input[b][c][hw]^2   (fp32 exact)
// block: 256 threads handles 64 pixels; thread (q = t&15 -> pixel quad, part = t>>4 -> 32 channels)
__global__ __launch_bounds__(256) void s2_kernel(const float* __restrict__ in,
                                                 float* __restrict__ s2) {
    const int t = threadIdx.x;
    const int q = t & 15;
    const int part = t >> 4;
    const int m0 = blockIdx.x * 64 + q * 4;
    const uint32_t b  = (uint32_t)m0 / 784u;
    const uint32_t hw = (uint32_t)m0 % 784u;
    const float* base = in + (size_t)b * IMG_STRIDE + hw;

    float4 acc = make_float4(0.f, 0.f, 0.f, 0.f);
    const int c0 = part * 32;
#pragma unroll 4
    for (int c = c0; c < c0 + 32; ++c) {
        float4 v = *(const float4*)(base + (size_t)c * HW);
        acc.x = fmaf(v.x, v.x, acc.x);
        acc.y = fmaf(v.y, v.y, acc.y);
        acc.z = fmaf(v.z, v.z, acc.z);
        acc.w = fmaf(v.w, v.w, acc.w);
    }
    __shared__ float red[16][64];
    red[part][q * 4 + 0] = acc.x;
    red[part][q * 4 + 1] = acc.y;
    red[part][q * 4 + 2] = acc.z;
    red[part][q * 4 + 3] = acc.w;
    __syncthreads();
    if (t < 64) {
        float s = 0.f;
#pragma unroll
        for (int p = 0; p < 16; ++p) s += red[p][t];
        s2[blockIdx.x * 64 + t] = s;
    }
}

// ---------------------------------------------------------------------------
// w2[p] = sum_c w[p][c]^2 ; one wave per p
__global__ __launch_bounds__(256) void w2_kernel(const float* __restrict__ w,
                                                 float* __restrict__ w2) {
    const int wave = threadIdx.x >> 6, lane = threadIdx.x & 63;
    const int p = blockIdx.x * 4 + wave;
    const float* base = w + (size_t)p * C_IN + lane * 8;
    float4 a = *(const float4*)base;
    float4 c = *(const float4*)(base + 4);
    float s = a.x*a.x + a.y*a.y + a.z*a.z + a.w*a.w
            + c.x*c.x + c.y*c.y + c.z*c.z + c.w*c.w;
#pragma unroll
    for (int off = 32; off; off >>= 1) s += __shfl_down(s, off);
    if (lane == 0) w2[p] = s;
}

// ---------------------------------------------------------------------------
// Fused GEMM: out[m][n] = relu(s2[m] - 2*sum_k A[m][k]*B[n][k] + w2[n])
// A[m][k] = input (k strided by HW), B[n][k] = weights (k contiguous)
__global__ __launch_bounds__(256) void gemm_kernel(const float* __restrict__ in,
                                                   const float* __restrict__ w,
                                                   const float* __restrict__ s2,
                                                   const float* __restrict__ w2,
                                                   float* __restrict__ out) {
    __shared__ __align__(16) short As[BM * BK];
    __shared__ __align__(16) short Bs[BN * BK];

    const int t  = threadIdx.x;
    const int bm = blockIdx.x;    // 196 M-tiles (fast-varying: B-panel reuse in L2, A streams once)
    const int bn = blockIdx.y;    // 16 N-tiles

    // ---- A staging: thread covers row (t&127), k-quads ((t>>7)+2*it)*4
    const int a_m = t & 127;
    const int m_g = bm * BM + a_m;
    const uint32_t ab  = (uint32_t)m_g / 784u;
    const uint32_t ahw = (uint32_t)m_g % 784u;
    const float* a_base = in + (size_t)ab * IMG_STRIDE + ahw;
    const int a_kq0 = (t >> 7) * 4;

    // ---- B staging: thread covers row n=(t>>1), k-half (t&1)*32
    const int b_n  = t >> 1;
    const int b_kh = (t & 1) * 32;
    const int n_g  = bn * BN + b_n;
    const bool n_ok = (n_g < N_TOT);
    const float* b_base = w + (size_t)n_g * C_IN + b_kh;

    // ---- wave -> 64x64 sub-tile
    const int wave = t >> 6, lane = t & 63;
    const int wm = (wave >> 1) * 64;
    const int wn = (wave & 1) * 64;
    const int lr = lane & 15;   // frag row (A) / col (B) / col (D)
    const int lg = lane >> 4;   // k-group; D row group

    f32x4 acc[4][4] = {};

    for (int k0 = 0; k0 < C_IN; k0 += BK) {
        // stage A tile (fp32 -> bf16)
#pragma unroll
        for (int it = 0; it < 8; ++it) {
            const int kq = a_kq0 + it * 8;
            const float* p = a_base + (size_t)(k0 + kq) * HW;
            float x0 = p[0], x1 = p[HW], x2 = p[2 * HW], x3 = p[3 * HW];
            ushort4 v;
            v.x = f2bf(x0); v.y = f2bf(x1); v.z = f2bf(x2); v.w = f2bf(x3);
            *(ushort4*)&As[a_m * BK + kq] = v;
        }
        // stage B tile
#pragma unroll
        for (int it = 0; it < 8; ++it) {
            float4 x = n_ok ? *(const float4*)(b_base + k0 + it * 4)
                            : make_float4(0.f, 0.f, 0.f, 0.f);
            ushort4 v;
            v.x = f2bf(x.x); v.y = f2bf(x.y); v.z = f2bf(x.z); v.w = f2bf(x.w);
            *(ushort4*)&Bs[b_n * BK + b_kh + it * 4] = v;
        }
        __syncthreads();

#pragma unroll
        for (int kk2 = 0; kk2 < 2; ++kk2) {
            bf16x8 af[4], bfr[4];
#pragma unroll
            for (int i = 0; i < 4; ++i)
                af[i] = *(bf16x8*)&As[(wm + i * 16 + lr) * BK + kk2 * 32 + lg * 8];
#pragma unroll
            for (int i = 0; i < 4; ++i)
                bfr[i] = *(bf16x8*)&Bs[(wn + i * 16 + lr) * BK + kk2 * 32 + lg * 8];
#pragma unroll
            for (int i = 0; i < 4; ++i)
#pragma unroll
                for (int j = 0; j < 4; ++j)
                    acc[i][j] = __builtin_amdgcn_mfma_f32_16x16x32_bf16(
                        af[i], bfr[j], acc[i][j], 0, 0, 0);
        }
        __syncthreads();
    }

    // ---- epilogue: relu(s2 - 2*acc + w2), float4 stores over 4 consecutive m
#pragma unroll
    for (int i = 0; i < 4; ++i) {
        const int m_r = bm * BM + wm + i * 16 + lg * 4;   // 4-aligned; 784%4==0 -> same batch
        const float4 s2v = *(const float4*)(s2 + m_r);
        const uint32_t ob  = (uint32_t)m_r / 784u;
        const uint32_t ohw = (uint32_t)m_r % 784u;
        float* obase = out + (size_t)ob * OUT_BATCH + ohw;
#pragma unroll
        for (int j = 0; j < 4; ++j) {
            const int n_o = bn * BN + wn + j * 16 + lr;
            if (n_o < N_TOT) {
                const float wv = w2[n_o];
                const f32x4 a = acc[i][j];
                float4 r;
                r.x = fmaxf(s2v.x - 2.f * a.x + wv, 0.f);
                r.y = fmaxf(s2v.y - 2.f * a.y + wv, 0.f);
                r.z = fmaxf(s2v.z - 2.f * a.z + wv, 0.f);
                r.w = fmaxf(s2v.w - 2.f * a.w + wv, 0.f);
                *(float4*)(obase + (size_t)n_o * HW) = r;
            }
        }
    }
}

// ---------------------------------------------------------------------------
extern "C" void kernel_launch(void* const* d_in, const int* in_sizes, int n_in,
                              void* d_out, int out_size, void* d_ws, size_t ws_size,
                              hipStream_t stream) {
    const float* in = (const float*)d_in[0];   // [32,512,28,28] fp32
    const float* w  = (const float*)d_in[1];   // [2000,512,1,1] fp32
    float* out = (float*)d_out;                // [32,2000,28,28] fp32

    float* s2 = (float*)d_ws;                  // 25088 floats
    float* w2 = s2 + M_TOT;                    // 2000 floats  (~108 KB total)

    s2_kernel<<<M_TOT / 64, 256, 0, stream>>>(in, s2);
    w2_kernel<<<N_TOT / 4, 256, 0, stream>>>(w, w2);

    dim3 grid(M_TOT / BM, (N_TOT + BN - 1) / BN);   // (196, 16)
    gemm_kernel<<<grid, 256, 0, stream>>>(in, w, s2, w2, out);
}

// Round 2
// 147.317 us; speedup vs baseline: 2.3935x; 2.3935x over previous
//
#include <hip/hip_runtime.h>
#include <stdint.h>

// Problem constants
constexpr int C_IN  = 512;
constexpr int HW    = 784;            // 28*28 (1x1 conv, VALID -> same spatial)
constexpr int NB    = 32;             // batch
constexpr int M_TOT = NB * HW;        // 25088
constexpr int N_TOT = 2000;           // out channels
constexpr int NPAD  = 2048;           // padded N for boundless staging
constexpr int IMG_STRIDE = C_IN * HW; // floats per input image
constexpr int OUT_BATCH  = N_TOT * HW;

// GEMM tiling
#define BM 128
#define BN 128
#define BK 64

typedef __attribute__((ext_vector_type(8))) short bf16x8;
typedef __attribute__((ext_vector_type(4))) float f32x4;

__device__ __forceinline__ uint16_t f2bf(float f) {
    union { float f; uint32_t u; } x; x.f = f;
    return (uint16_t)((x.u + 0x8000u) >> 16);   // round-half-up to bf16 (no NaN in data)
}

__device__ __forceinline__ void gload_lds16(const void* g, void* l) {
    __builtin_amdgcn_global_load_lds(
        (const __attribute__((address_space(1))) void*)g,
        (__attribute__((address_space(3))) void*)l, 16, 0, 0);
}

// ---------------------------------------------------------------------------
// prep_a: Abf[m][k] = bf16(input), transposed through LDS, fused s2[m]=sum_k x^2
// block: 256 threads handles 64 m x 512 k. thread: q=t&15 (m-quad), part=t>>4 (32 k's)
__global__ __launch_bounds__(256) void prep_a_kernel(const float* __restrict__ in,
                                                     short* __restrict__ Abf,
                                                     float* __restrict__ s2) {
    __shared__ __align__(16) char T[64 * 512 * 2];   // 64KB bf16 tile, swizzled
    __shared__ float red[16][64];

    const int t = threadIdx.x;
    const int q = t & 15;
    const int part = t >> 4;
    const int m0q = blockIdx.x * 64 + q * 4;          // 4-aligned: never crosses image bound
    const uint32_t b  = (uint32_t)m0q / 784u;
    const uint32_t hw = (uint32_t)m0q % 784u;
    const float* base = in + (size_t)b * IMG_STRIDE + hw;

    float4 acc = make_float4(0.f, 0.f, 0.f, 0.f);
    const int c0 = part * 32;
#pragma unroll 4
    for (int c = c0; c < c0 + 32; ++c) {
        float4 v = *(const float4*)(base + (size_t)c * HW);
        acc.x = fmaf(v.x, v.x, acc.x);
        acc.y = fmaf(v.y, v.y, acc.y);
        acc.z = fmaf(v.z, v.z, acc.z);
        acc.w = fmaf(v.w, v.w, acc.w);
        uint16_t vals[4] = { f2bf(v.x), f2bf(v.y), f2bf(v.z), f2bf(v.w) };
        const uint32_t by0 = (uint32_t)(q * 4) * 1024u + (uint32_t)c * 2u;
#pragma unroll
        for (int j = 0; j < 4; ++j) {
            uint32_t bb = by0 + (uint32_t)j * 1024u;
            bb ^= ((bb >> 12) & 7u) << 4;             // row-based XOR swizzle
            *(uint16_t*)(T + bb) = vals[j];
        }
    }
    red[part][q * 4 + 0] = acc.x;
    red[part][q * 4 + 1] = acc.y;
    red[part][q * 4 + 2] = acc.z;
    red[part][q * 4 + 3] = acc.w;
    __syncthreads();
    if (t < 64) {
        float s = 0.f;
#pragma unroll
        for (int p = 0; p < 16; ++p) s += red[p][t];
        s2[blockIdx.x * 64 + t] = s;
    }
    // write out 64 rows x 512 bf16, coalesced bf16x8
    short* dst = Abf + (size_t)blockIdx.x * 64 * 512;
#pragma unroll
    for (int i = 0; i < 16; ++i) {
        const int idx = i * 256 + t;
        const int row = idx >> 6, ch = idx & 63;
        uint32_t bb = (uint32_t)row * 1024u + (uint32_t)ch * 16u;
        bb ^= ((bb >> 12) & 7u) << 4;
        bf16x8 v = *(bf16x8*)(T + bb);
        *(bf16x8*)(dst + (size_t)row * 512 + ch * 8) = v;
    }
}

// ---------------------------------------------------------------------------
// prep_w: Wbf[p][k] = bf16(w), rows >= N_TOT zeroed; fused w2[p] = sum_k w^2
__global__ __launch_bounds__(256) void prep_w_kernel(const float* __restrict__ w,
                                                     short* __restrict__ Wbf,
                                                     float* __restrict__ w2) {
    const int wv = threadIdx.x >> 6, lane = threadIdx.x & 63;
    const int p = blockIdx.x * 4 + wv;
    bf16x8 o = (bf16x8)0;
    float s = 0.f;
    if (p < N_TOT) {
        const float* base = w + (size_t)p * C_IN + lane * 8;
        float4 a = *(const float4*)base;
        float4 c = *(const float4*)(base + 4);
        s = a.x*a.x + a.y*a.y + a.z*a.z + a.w*a.w
          + c.x*c.x + c.y*c.y + c.z*c.z + c.w*c.w;
        o[0] = (short)f2bf(a.x); o[1] = (short)f2bf(a.y);
        o[2] = (short)f2bf(a.z); o[3] = (short)f2bf(a.w);
        o[4] = (short)f2bf(c.x); o[5] = (short)f2bf(c.y);
        o[6] = (short)f2bf(c.z); o[7] = (short)f2bf(c.w);
    }
    *(bf16x8*)(Wbf + (size_t)p * C_IN + lane * 8) = o;
#pragma unroll
    for (int off = 32; off; off >>= 1) s += __shfl_down(s, off);
    if (lane == 0) w2[p] = s;
}

// ---------------------------------------------------------------------------
// gemm2: pure bf16 GEMM, m97 structure: global_load_lds width-16 staging,
// linear LDS, 128x128x64 tile, fused relu(s2 - 2*acc + w2) epilogue.
__global__ __launch_bounds__(256) void gemm2_kernel(const short* __restrict__ Abf,
                                                    const short* __restrict__ Wbf,
                                                    const float* __restrict__ s2,
                                                    const float* __restrict__ w2,
                                                    float* __restrict__ out) {
    __shared__ __align__(16) short As[BM * BK];
    __shared__ __align__(16) short Bs[BN * BK];

    const int t = threadIdx.x;
    const int wv = t >> 6, lane = t & 63;
    const int bm = blockIdx.x;          // fast-varying: B panel L2-hot, A streams
    const int bn = blockIdx.y;

    const short* Ab = Abf + (size_t)bm * BM * C_IN;
    const short* Bb = Wbf + (size_t)bn * BN * C_IN;
    const int lrw = lane >> 3;          // row within 8-row segment
    const int lk  = (lane & 7) * 8;     // k elems within row

    const int wm = (wv >> 1) * 64;
    const int wn = (wv & 1) * 64;
    const int lr = lane & 15;
    const int lg = lane >> 4;

    f32x4 acc[4][4] = {};

    for (int k0 = 0; k0 < C_IN; k0 += BK) {
#pragma unroll
        for (int i = 0; i < 4; ++i) {
            const int seg = i * 4 + wv;
            gload_lds16(Ab + (size_t)(seg * 8 + lrw) * C_IN + k0 + lk, As + seg * 512);
            gload_lds16(Bb + (size_t)(seg * 8 + lrw) * C_IN + k0 + lk, Bs + seg * 512);
        }
        __syncthreads();

#pragma unroll
        for (int kk2 = 0; kk2 < 2; ++kk2) {
            bf16x8 af[4], bfr[4];
#pragma unroll
            for (int i = 0; i < 4; ++i)
                af[i] = *(bf16x8*)&As[(wm + i * 16 + lr) * BK + kk2 * 32 + lg * 8];
#pragma unroll
            for (int i = 0; i < 4; ++i)
                bfr[i] = *(bf16x8*)&Bs[(wn + i * 16 + lr) * BK + kk2 * 32 + lg * 8];
#pragma unroll
            for (int i = 0; i < 4; ++i)
#pragma unroll
                for (int j = 0; j < 4; ++j)
                    acc[i][j] = __builtin_amdgcn_mfma_f32_16x16x32_bf16(
                        af[i], bfr[j], acc[i][j], 0, 0, 0);
        }
        __syncthreads();
    }

    // epilogue: relu(s2 - 2*acc + w2), float4 stores over 4 consecutive m
#pragma unroll
    for (int i = 0; i < 4; ++i) {
        const int m_r = bm * BM + wm + i * 16 + lg * 4;   // 4-aligned; 784%4==0
        const float4 s2v = *(const float4*)(s2 + m_r);
        const uint32_t ob  = (uint32_t)m_r / 784u;
        const uint32_t ohw = (uint32_t)m_r % 784u;
        float* obase = out + (size_t)ob * OUT_BATCH + ohw;
#pragma unroll
        for (int j = 0; j < 4; ++j) {
            const int n_o = bn * BN + wn + j * 16 + lr;
            if (n_o < N_TOT) {
                const float wvv = w2[n_o];
                const f32x4 a = acc[i][j];
                float4 r;
                r.x = fmaxf(s2v.x - 2.f * a.x + wvv, 0.f);
                r.y = fmaxf(s2v.y - 2.f * a.y + wvv, 0.f);
                r.z = fmaxf(s2v.z - 2.f * a.z + wvv, 0.f);
                r.w = fmaxf(s2v.w - 2.f * a.w + wvv, 0.f);
                *(float4*)(obase + (size_t)n_o * HW) = r;
            }
        }
    }
}

// ===========================================================================
// Fallback path (round-1 kernels) if d_ws is too small for the bf16 matrices
// ===========================================================================
__global__ __launch_bounds__(256) void s2_kernel(const float* __restrict__ in,
                                                 float* __restrict__ s2) {
    const int t = threadIdx.x;
    const int q = t & 15;
    const int part = t >> 4;
    const int m0 = blockIdx.x * 64 + q * 4;
    const uint32_t b  = (uint32_t)m0 / 784u;
    const uint32_t hw = (uint32_t)m0 % 784u;
    const float* base = in + (size_t)b * IMG_STRIDE + hw;

    float4 acc = make_float4(0.f, 0.f, 0.f, 0.f);
    const int c0 = part * 32;
#pragma unroll 4
    for (int c = c0; c < c0 + 32; ++c) {
        float4 v = *(const float4*)(base + (size_t)c * HW);
        acc.x = fmaf(v.x, v.x, acc.x);
        acc.y = fmaf(v.y, v.y, acc.y);
        acc.z = fmaf(v.z, v.z, acc.z);
        acc.w = fmaf(v.w, v.w, acc.w);
    }
    __shared__ float red[16][64];
    red[part][q * 4 + 0] = acc.x;
    red[part][q * 4 + 1] = acc.y;
    red[part][q * 4 + 2] = acc.z;
    red[part][q * 4 + 3] = acc.w;
    __syncthreads();
    if (t < 64) {
        float s = 0.f;
#pragma unroll
        for (int p = 0; p < 16; ++p) s += red[p][t];
        s2[blockIdx.x * 64 + t] = s;
    }
}

__global__ __launch_bounds__(256) void w2_kernel(const float* __restrict__ w,
                                                 float* __restrict__ w2) {
    const int wave = threadIdx.x >> 6, lane = threadIdx.x & 63;
    const int p = blockIdx.x * 4 + wave;
    const float* base = w + (size_t)p * C_IN + lane * 8;
    float4 a = *(const float4*)base;
    float4 c = *(const float4*)(base + 4);
    float s = a.x*a.x + a.y*a.y + a.z*a.z + a.w*a.w
            + c.x*c.x + c.y*c.y + c.z*c.z + c.w*c.w;
#pragma unroll
    for (int off = 32; off; off >>= 1) s += __shfl_down(s, off);
    if (lane == 0) w2[p] = s;
}

__global__ __launch_bounds__(256) void gemm_kernel(const float* __restrict__ in,
                                                   const float* __restrict__ w,
                                                   const float* __restrict__ s2,
                                                   const float* __restrict__ w2,
                                                   float* __restrict__ out) {
    __shared__ __align__(16) short As[BM * BK];
    __shared__ __align__(16) short Bs[BN * BK];

    const int t  = threadIdx.x;
    const int bm = blockIdx.x;
    const int bn = blockIdx.y;

    const int a_m = t & 127;
    const int m_g = bm * BM + a_m;
    const uint32_t ab  = (uint32_t)m_g / 784u;
    const uint32_t ahw = (uint32_t)m_g % 784u;
    const float* a_base = in + (size_t)ab * IMG_STRIDE + ahw;
    const int a_kq0 = (t >> 7) * 4;

    const int b_n  = t >> 1;
    const int b_kh = (t & 1) * 32;
    const int n_g  = bn * BN + b_n;
    const bool n_ok = (n_g < N_TOT);
    const float* b_base = w + (size_t)n_g * C_IN + b_kh;

    const int wave = t >> 6, lane = t & 63;
    const int wm = (wave >> 1) * 64;
    const int wn = (wave & 1) * 64;
    const int lr = lane & 15;
    const int lg = lane >> 4;

    f32x4 acc[4][4] = {};

    for (int k0 = 0; k0 < C_IN; k0 += BK) {
#pragma unroll
        for (int it = 0; it < 8; ++it) {
            const int kq = a_kq0 + it * 8;
            const float* p = a_base + (size_t)(k0 + kq) * HW;
            float x0 = p[0], x1 = p[HW], x2 = p[2 * HW], x3 = p[3 * HW];
            ushort4 v;
            v.x = f2bf(x0); v.y = f2bf(x1); v.z = f2bf(x2); v.w = f2bf(x3);
            *(ushort4*)&As[a_m * BK + kq] = v;
        }
#pragma unroll
        for (int it = 0; it < 8; ++it) {
            float4 x = n_ok ? *(const float4*)(b_base + k0 + it * 4)
                            : make_float4(0.f, 0.f, 0.f, 0.f);
            ushort4 v;
            v.x = f2bf(x.x); v.y = f2bf(x.y); v.z = f2bf(x.z); v.w = f2bf(x.w);
            *(ushort4*)&Bs[b_n * BK + b_kh + it * 4] = v;
        }
        __syncthreads();

#pragma unroll
        for (int kk2 = 0; kk2 < 2; ++kk2) {
            bf16x8 af[4], bfr[4];
#pragma unroll
            for (int i = 0; i < 4; ++i)
                af[i] = *(bf16x8*)&As[(wm + i * 16 + lr) * BK + kk2 * 32 + lg * 8];
#pragma unroll
            for (int i = 0; i < 4; ++i)
                bfr[i] = *(bf16x8*)&Bs[(wn + i * 16 + lr) * BK + kk2 * 32 + lg * 8];
#pragma unroll
            for (int i = 0; i < 4; ++i)
#pragma unroll
                for (int j = 0; j < 4; ++j)
                    acc[i][j] = __builtin_amdgcn_mfma_f32_16x16x32_bf16(
                        af[i], bfr[j], acc[i][j], 0, 0, 0);
        }
        __syncthreads();
    }

#pragma unroll
    for (int i = 0; i < 4; ++i) {
        const int m_r = bm * BM + wm + i * 16 + lg * 4;
        const float4 s2v = *(const float4*)(s2 + m_r);
        const uint32_t ob  = (uint32_t)m_r / 784u;
        const uint32_t ohw = (uint32_t)m_r % 784u;
        float* obase = out + (size_t)ob * OUT_BATCH + ohw;
#pragma unroll
        for (int j = 0; j < 4; ++j) {
            const int n_o = bn * BN + wn + j * 16 + lr;
            if (n_o < N_TOT) {
                const float wvv = w2[n_o];
                const f32x4 a = acc[i][j];
                float4 r;
                r.x = fmaxf(s2v.x - 2.f * a.x + wvv, 0.f);
                r.y = fmaxf(s2v.y - 2.f * a.y + wvv, 0.f);
                r.z = fmaxf(s2v.z - 2.f * a.z + wvv, 0.f);
                r.w = fmaxf(s2v.w - 2.f * a.w + wvv, 0.f);
                *(float4*)(obase + (size_t)n_o * HW) = r;
            }
        }
    }
}

// ---------------------------------------------------------------------------
extern "C" void kernel_launch(void* const* d_in, const int* in_sizes, int n_in,
                              void* d_out, int out_size, void* d_ws, size_t ws_size,
                              hipStream_t stream) {
    const float* in = (const float*)d_in[0];   // [32,512,28,28] fp32
    const float* w  = (const float*)d_in[1];   // [2000,512,1,1] fp32
    float* out = (float*)d_out;                // [32,2000,28,28] fp32

    const size_t offA  = 0;
    const size_t offW  = offA + (size_t)M_TOT * C_IN * sizeof(short);   // 25.7 MB
    const size_t offS2 = offW + (size_t)NPAD * C_IN * sizeof(short);    // +2.1 MB
    const size_t offW2 = offS2 + (size_t)M_TOT * sizeof(float);
    const size_t need  = offW2 + (size_t)NPAD * sizeof(float);

    if (ws_size >= need) {
        short* Abf = (short*)((char*)d_ws + offA);
        short* Wbf = (short*)((char*)d_ws + offW);
        float* s2  = (float*)((char*)d_ws + offS2);
        float* w2  = (float*)((char*)d_ws + offW2);

        prep_a_kernel<<<M_TOT / 64, 256, 0, stream>>>(in, Abf, s2);
        prep_w_kernel<<<NPAD / 4, 256, 0, stream>>>(w, Wbf, w2);

        dim3 grid(M_TOT / BM, NPAD / BN);   // (196, 16)
        gemm2_kernel<<<grid, 256, 0, stream>>>(Abf, Wbf, s2, w2, out);
    } else {
        float* s2 = (float*)d_ws;
        float* w2 = s2 + M_TOT;
        s2_kernel<<<M_TOT / 64, 256, 0, stream>>>(in, s2);
        w2_kernel<<<N_TOT / 4, 256, 0, stream>>>(w, w2);
        dim3 grid(M_TOT / BM, (N_TOT + BN - 1) / BN);
        gemm_kernel<<<grid, 256, 0, stream>>>(in, w, s2, w2, out);
    }
}

// Round 3
// 126.154 us; speedup vs baseline: 2.7950x; 1.1678x over previous
//
#include <hip/hip_runtime.h>
#include <stdint.h>

// Problem constants
constexpr int C_IN  = 512;
constexpr int HW    = 784;            // 28*28
constexpr int NB    = 32;
constexpr int M_TOT = NB * HW;        // 25088
constexpr int N_TOT = 2000;
constexpr int NPAD  = 2048;
constexpr int IMG_STRIDE = C_IN * HW;
constexpr int OUT_BATCH  = N_TOT * HW;

// GEMM tiling (256x256x64, 8 waves)
constexpr int TBM = 256;
constexpr int TBN = 256;
constexpr int TBK = 64;

typedef __attribute__((ext_vector_type(8))) short bf16x8;
typedef __attribute__((ext_vector_type(4))) float f32x4;

__device__ __forceinline__ uint16_t f2bf(float f) {
    union { float f; uint32_t u; } x; x.f = f;
    return (uint16_t)((x.u + 0x8000u) >> 16);
}

__device__ __forceinline__ void gload_lds16(const void* g, void* l) {
    __builtin_amdgcn_global_load_lds(
        (const __attribute__((address_space(1))) void*)g,
        (__attribute__((address_space(3))) void*)l, 16, 0, 0);
}

// ---------------------------------------------------------------------------
// prep_a: Abf[m][k] = bf16(input) transposed through LDS; fused s2[m]
__global__ __launch_bounds__(256) void prep_a_kernel(const float* __restrict__ in,
                                                     short* __restrict__ Abf,
                                                     float* __restrict__ s2) {
    __shared__ __align__(16) char T[64 * 512 * 2];
    __shared__ float red[16][64];

    const int t = threadIdx.x;
    const int q = t & 15;
    const int part = t >> 4;
    const int m0q = blockIdx.x * 64 + q * 4;
    const uint32_t b  = (uint32_t)m0q / 784u;
    const uint32_t hw = (uint32_t)m0q % 784u;
    const float* base = in + (size_t)b * IMG_STRIDE + hw;

    float4 acc = make_float4(0.f, 0.f, 0.f, 0.f);
    const int c0 = part * 32;
#pragma unroll 4
    for (int c = c0; c < c0 + 32; ++c) {
        float4 v = *(const float4*)(base + (size_t)c * HW);
        acc.x = fmaf(v.x, v.x, acc.x);
        acc.y = fmaf(v.y, v.y, acc.y);
        acc.z = fmaf(v.z, v.z, acc.z);
        acc.w = fmaf(v.w, v.w, acc.w);
        uint16_t vals[4] = { f2bf(v.x), f2bf(v.y), f2bf(v.z), f2bf(v.w) };
        const uint32_t by0 = (uint32_t)(q * 4) * 1024u + (uint32_t)c * 2u;
#pragma unroll
        for (int j = 0; j < 4; ++j) {
            uint32_t bb = by0 + (uint32_t)j * 1024u;
            bb ^= ((bb >> 12) & 7u) << 4;
            *(uint16_t*)(T + bb) = vals[j];
        }
    }
    red[part][q * 4 + 0] = acc.x;
    red[part][q * 4 + 1] = acc.y;
    red[part][q * 4 + 2] = acc.z;
    red[part][q * 4 + 3] = acc.w;
    __syncthreads();
    if (t < 64) {
        float s = 0.f;
#pragma unroll
        for (int p = 0; p < 16; ++p) s += red[p][t];
        s2[blockIdx.x * 64 + t] = s;
    }
    short* dst = Abf + (size_t)blockIdx.x * 64 * 512;
#pragma unroll
    for (int i = 0; i < 16; ++i) {
        const int idx = i * 256 + t;
        const int row = idx >> 6, ch = idx & 63;
        uint32_t bb = (uint32_t)row * 1024u + (uint32_t)ch * 16u;
        bb ^= ((bb >> 12) & 7u) << 4;
        bf16x8 v = *(bf16x8*)(T + bb);
        *(bf16x8*)(dst + (size_t)row * 512 + ch * 8) = v;
    }
}

// ---------------------------------------------------------------------------
// prep_w: Wbf[p][k] = bf16(w), rows >= N_TOT zeroed; fused w2[p]
__global__ __launch_bounds__(256) void prep_w_kernel(const float* __restrict__ w,
                                                     short* __restrict__ Wbf,
                                                     float* __restrict__ w2) {
    const int wv = threadIdx.x >> 6, lane = threadIdx.x & 63;
    const int p = blockIdx.x * 4 + wv;
    bf16x8 o = (bf16x8)0;
    float s = 0.f;
    if (p < N_TOT) {
        const float* base = w + (size_t)p * C_IN + lane * 8;
        float4 a = *(const float4*)base;
        float4 c = *(const float4*)(base + 4);
        s = a.x*a.x + a.y*a.y + a.z*a.z + a.w*a.w
          + c.x*c.x + c.y*c.y + c.z*c.z + c.w*c.w;
        o[0] = (short)f2bf(a.x); o[1] = (short)f2bf(a.y);
        o[2] = (short)f2bf(a.z); o[3] = (short)f2bf(a.w);
        o[4] = (short)f2bf(c.x); o[5] = (short)f2bf(c.y);
        o[6] = (short)f2bf(c.z); o[7] = (short)f2bf(c.w);
    }
    *(bf16x8*)(Wbf + (size_t)p * C_IN + lane * 8) = o;
#pragma unroll
    for (int off = 32; off; off >>= 1) s += __shfl_down(s, off);
    if (lane == 0) w2[p] = s;
}

// ---------------------------------------------------------------------------
// gemm3: 256x256x64 double-buffered pipeline, counted vmcnt, T2 swizzle,
// setprio around MFMA clusters, fused relu(s2 - 2*acc + w2) epilogue.
__global__ __launch_bounds__(512, 2) void gemm3_kernel(const short* __restrict__ Abf,
                                                       const short* __restrict__ Wbf,
                                                       const float* __restrict__ s2,
                                                       const float* __restrict__ w2,
                                                       float* __restrict__ out) {
    __shared__ __align__(16) char smem[131072];   // 2 bufs x (A 32K + B 32K)

    const int t = threadIdx.x;
    const int wv = t >> 6, lane = t & 63;
    const int lr = lane & 15, lg = lane >> 4;

    // XCD mapping: bn = bid&7 -> each XCD owns one bn column (B panel L2-hot)
    const int orig = blockIdx.x;
    const int bn = orig & 7;
    const int bm = orig >> 3;

    const short* Ab = Abf + (size_t)bm * TBM * C_IN;
    const short* Bb = Wbf + (size_t)bn * TBN * C_IN;

    // staging geometry: instr i covers rows i*64 + wv*8 + (lane>>3), slot lane&7.
    // LDS linear dest; source pre-swizzled: src slot = (lane&7) ^ ((lane>>3)&7)
    const int srow = wv * 8 + (lane >> 3);
    const int lsw  = (lane & 7) ^ ((lane >> 3) & 7);
    const short* Asrc = Ab + (size_t)srow * C_IN + lsw * 8;
    const short* Bsrc = Bb + (size_t)srow * C_IN + lsw * 8;
    char* aldw = smem + wv * 1024;            // + buf*65536 + i*8192
    char* bldw = smem + 32768 + wv * 1024;

    // wave -> output subtile
    const int wm = (wv >> 2) * 128;           // warp_m in {0,1}
    const int wn = (wv & 3) * 64;             // warp_n in {0..3}

    // swizzled ds_read offsets: row = (wm|wn) + frag*16 + lr, slot = (kk*4+lg)^(lr&7)
    const int aoff = (wm + lr) * 128;
    const int boff = 32768 + (wn + lr) * 128;
    const int sl0  = ((lg ^ (lr & 7)) * 16);  // kk=0 slot byte; kk=1 = sl0^64

    f32x4 acc[8][4] = {};

#define STAGE(tt, buf)                                                          \
    do {                                                                        \
        const short* As_ = Asrc + (tt) * TBK;                                   \
        const short* Bs_ = Bsrc + (tt) * TBK;                                   \
        char* al_ = aldw + (buf) * 65536;                                       \
        char* bl_ = bldw + (buf) * 65536;                                       \
        gload_lds16(As_,                 al_);                                  \
        gload_lds16(As_ +  64 * C_IN,    al_ + 8192);                           \
        gload_lds16(As_ + 128 * C_IN,    al_ + 16384);                          \
        gload_lds16(As_ + 192 * C_IN,    al_ + 24576);                          \
        gload_lds16(Bs_,                 bl_);                                  \
        gload_lds16(Bs_ +  64 * C_IN,    bl_ + 8192);                           \
        gload_lds16(Bs_ + 128 * C_IN,    bl_ + 16384);                          \
        gload_lds16(Bs_ + 192 * C_IN,    bl_ + 24576);                          \
    } while (0)

    // prologue: prefetch K-tiles 0 and 1
    STAGE(0, 0);
    STAGE(1, 1);
    asm volatile("s_waitcnt vmcnt(8)" ::: "memory");   // tile 0 landed
    __builtin_amdgcn_sched_barrier(0);
    __builtin_amdgcn_s_barrier();
    __builtin_amdgcn_sched_barrier(0);

#pragma unroll
    for (int kt = 0; kt < 8; ++kt) {
        const int buf = kt & 1;
        const char* Al = smem + buf * 65536;
        bf16x8 bfrag[4][2], afrag[4][2];

        // B frags + A half0
#pragma unroll
        for (int n = 0; n < 4; ++n) {
            bfrag[n][0] = *(const bf16x8*)(Al + boff + n * 2048 + sl0);
            bfrag[n][1] = *(const bf16x8*)(Al + boff + n * 2048 + (sl0 ^ 64));
        }
#pragma unroll
        for (int m = 0; m < 4; ++m) {
            afrag[m][0] = *(const bf16x8*)(Al + aoff + m * 2048 + sl0);
            afrag[m][1] = *(const bf16x8*)(Al + aoff + m * 2048 + (sl0 ^ 64));
        }
        __builtin_amdgcn_s_setprio(1);
#pragma unroll
        for (int m = 0; m < 4; ++m)
#pragma unroll
            for (int n = 0; n < 4; ++n) {
                acc[m][n] = __builtin_amdgcn_mfma_f32_16x16x32_bf16(
                    afrag[m][0], bfrag[n][0], acc[m][n], 0, 0, 0);
                acc[m][n] = __builtin_amdgcn_mfma_f32_16x16x32_bf16(
                    afrag[m][1], bfrag[n][1], acc[m][n], 0, 0, 0);
            }
        __builtin_amdgcn_s_setprio(0);

        // A half1 (reuse afrag regs)
#pragma unroll
        for (int m = 0; m < 4; ++m) {
            afrag[m][0] = *(const bf16x8*)(Al + aoff + (m + 4) * 2048 + sl0);
            afrag[m][1] = *(const bf16x8*)(Al + aoff + (m + 4) * 2048 + (sl0 ^ 64));
        }
        asm volatile("s_waitcnt lgkmcnt(0)" ::: "memory");  // my reads of buf done
        __builtin_amdgcn_sched_barrier(0);
        __builtin_amdgcn_s_barrier();                       // everyone done reading buf
        __builtin_amdgcn_sched_barrier(0);

        if (kt + 2 < 8) STAGE(kt + 2, buf);                 // overwrite freed buffer

        __builtin_amdgcn_s_setprio(1);
#pragma unroll
        for (int m = 0; m < 4; ++m)
#pragma unroll
            for (int n = 0; n < 4; ++n) {
                acc[m + 4][n] = __builtin_amdgcn_mfma_f32_16x16x32_bf16(
                    afrag[m][0], bfrag[n][0], acc[m + 4][n], 0, 0, 0);
                acc[m + 4][n] = __builtin_amdgcn_mfma_f32_16x16x32_bf16(
                    afrag[m][1], bfrag[n][1], acc[m + 4][n], 0, 0, 0);
            }
        __builtin_amdgcn_s_setprio(0);

        if (kt < 7) {
            if (kt + 2 < 8) {
                asm volatile("s_waitcnt vmcnt(8)" ::: "memory");  // tile kt+1 landed; kt+2 in flight
            } else {
                asm volatile("s_waitcnt vmcnt(0)" ::: "memory");  // last tile
            }
            __builtin_amdgcn_sched_barrier(0);
            __builtin_amdgcn_s_barrier();
            __builtin_amdgcn_sched_barrier(0);
        }
    }
#undef STAGE

    // epilogue: relu(s2 - 2*acc + w2), float4 over 4 consecutive m (hw-contig)
#pragma unroll
    for (int m = 0; m < 8; ++m) {
        const int m_r = bm * TBM + wm + m * 16 + lg * 4;   // 4-aligned, 784%4==0
        const float4 s2v = *(const float4*)(s2 + m_r);
        const uint32_t ob  = (uint32_t)m_r / 784u;
        const uint32_t ohw = (uint32_t)m_r % 784u;
        float* obase = out + (size_t)ob * OUT_BATCH + ohw;
#pragma unroll
        for (int n = 0; n < 4; ++n) {
            const int n_o = bn * TBN + wn + n * 16 + lr;
            if (n_o < N_TOT) {
                const float wvv = w2[n_o];
                const f32x4 a = acc[m][n];
                float4 r;
                r.x = fmaxf(s2v.x - 2.f * a.x + wvv, 0.f);
                r.y = fmaxf(s2v.y - 2.f * a.y + wvv, 0.f);
                r.z = fmaxf(s2v.z - 2.f * a.z + wvv, 0.f);
                r.w = fmaxf(s2v.w - 2.f * a.w + wvv, 0.f);
                *(float4*)(obase + (size_t)n_o * HW) = r;
            }
        }
    }
}

// ---------------------------------------------------------------------------
extern "C" void kernel_launch(void* const* d_in, const int* in_sizes, int n_in,
                              void* d_out, int out_size, void* d_ws, size_t ws_size,
                              hipStream_t stream) {
    const float* in = (const float*)d_in[0];   // [32,512,28,28] fp32
    const float* w  = (const float*)d_in[1];   // [2000,512,1,1] fp32
    float* out = (float*)d_out;                // [32,2000,28,28] fp32

    const size_t offA  = 0;
    const size_t offW  = offA + (size_t)M_TOT * C_IN * sizeof(short);   // 25.7 MB
    const size_t offS2 = offW + (size_t)NPAD * C_IN * sizeof(short);    // +2.1 MB
    const size_t offW2 = offS2 + (size_t)M_TOT * sizeof(float);

    short* Abf = (short*)((char*)d_ws + offA);
    short* Wbf = (short*)((char*)d_ws + offW);
    float* s2  = (float*)((char*)d_ws + offS2);
    float* w2  = (float*)((char*)d_ws + offW2);

    prep_a_kernel<<<M_TOT / 64, 256, 0, stream>>>(in, Abf, s2);
    prep_w_kernel<<<NPAD / 4, 256, 0, stream>>>(w, Wbf, w2);

    // 98 m-tiles x 8 n-tiles; bn = bid&7 -> per-XCD bn column
    gemm3_kernel<<<98 * 8, 512, 0, stream>>>(Abf, Wbf, s2, w2, out);
}